// Round 3
// baseline (368.584 us; speedup 1.0000x reference)
//
#include <hip/hip_runtime.h>

#define C_DIM 16
#define B_DIM 128
#define H_DIM 512
#define W_DIM 512
#define HW (H_DIM * W_DIM)      // 262144
#define BPS 16                  // blocks per sample
#define NBLK (B_DIM * BPS)      // 2048
#define TPB 256
#define VEC_PER_CHUNK (HW / 4 / BPS)   // 4096 float4 per block

// d_ws is re-poisoned to 0xAA bytes before every launch (harness contract),
// so the u32 arrival counter deterministically starts at 0xAAAAAAAA.
#define POISON_U32 0xAAAAAAAAu

__device__ __forceinline__ unsigned int mono_bits(float x) {
    unsigned int u = __float_as_uint(x);
    return (u & 0x80000000u) ? ~u : (u | 0x80000000u);
}

__device__ __forceinline__ unsigned long long pack_key(float v, unsigned int idx) {
    // high word: monotone value bits; low word: ~idx so LOWER index wins ties
    return ((unsigned long long)mono_bits(v) << 32) | (unsigned long long)(~idx);
}

__global__ __launch_bounds__(TPB) void fused_kernel(
        const float* __restrict__ heatmap,
        const float* __restrict__ pred,
        const float* __restrict__ gt,
        unsigned long long* __restrict__ part,   // [NBLK]
        unsigned int* __restrict__ counter,      // 1 u32, starts at POISON_U32
        float* __restrict__ out) {
    const int b     = blockIdx.x / BPS;
    const int chunk = blockIdx.x % BPS;
    const float4* hp = (const float4*)(heatmap + (size_t)b * HW);
    const int vbase = chunk * VEC_PER_CHUNK;

    unsigned long long k = 0ull;
    #pragma unroll 4
    for (int i = threadIdx.x; i < VEC_PER_CHUNK; i += TPB) {
        float4 v = hp[vbase + i];
        unsigned int e = (unsigned int)(vbase + i) * 4u;
        unsigned long long k0 = pack_key(v.x, e + 0u);
        unsigned long long k1 = pack_key(v.y, e + 1u);
        unsigned long long k2 = pack_key(v.z, e + 2u);
        unsigned long long k3 = pack_key(v.w, e + 3u);
        if (k1 > k0) k0 = k1;
        if (k3 > k2) k2 = k3;
        if (k2 > k0) k0 = k2;
        if (k0 > k)  k  = k0;
    }

    // wave(64) shuffle reduce
    #pragma unroll
    for (int off = 32; off > 0; off >>= 1) {
        unsigned long long o = __shfl_down(k, off, 64);
        if (o > k) k = o;
    }
    __shared__ unsigned long long smax[TPB / 64];
    __shared__ int s_last;
    const int lane = threadIdx.x & 63;
    const int wid  = threadIdx.x >> 6;
    if (lane == 0) smax[wid] = k;
    __syncthreads();
    if (threadIdx.x == 0) {
        k = smax[0];
        #pragma unroll
        for (int w = 1; w < TPB / 64; ++w)
            if (smax[w] > k) k = smax[w];
        // device-scope release store of this block's winning key
        __hip_atomic_store(&part[blockIdx.x], k, __ATOMIC_RELEASE,
                           __HIP_MEMORY_SCOPE_AGENT);
        unsigned int old = __hip_atomic_fetch_add(counter, 1u, __ATOMIC_ACQ_REL,
                                                  __HIP_MEMORY_SCOPE_AGENT);
        s_last = ((old - POISON_U32) == (unsigned)(NBLK - 1)) ? 1 : 0;
    }
    __syncthreads();
    if (!s_last) return;

    // ---- last-arriving block: final reduce + gather + loss ----
    float acc = 0.f;
    if (threadIdx.x < B_DIM) {
        const int s = threadIdx.x;           // one thread per sample
        unsigned long long kk = 0ull;
        #pragma unroll
        for (int j = 0; j < BPS; ++j) {
            // device-scope acquire load: per-XCD L2s are not coherent (G16)
            unsigned long long o = __hip_atomic_load(&part[s * BPS + j],
                                                     __ATOMIC_ACQUIRE,
                                                     __HIP_MEMORY_SCOPE_AGENT);
            if (o > kk) kk = o;
        }
        unsigned int idx = ~(unsigned int)(kk & 0xFFFFFFFFull);
        #pragma unroll
        for (int c = 0; c < C_DIM; ++c) {
            float d = pred[(size_t)c * HW + idx] - gt[s * C_DIM + c];
            acc += d * d;
        }
    }
    // block sum-reduce (threads >= B_DIM contribute 0)
    #pragma unroll
    for (int off = 32; off > 0; off >>= 1)
        acc += __shfl_down(acc, off, 64);
    __shared__ float spart[TPB / 64];
    if (lane == 0) spart[wid] = acc;
    __syncthreads();
    if (threadIdx.x == 0)
        out[0] = spart[0] + spart[1] + spart[2] + spart[3];
}

extern "C" void kernel_launch(void* const* d_in, const int* in_sizes, int n_in,
                              void* d_out, int out_size, void* d_ws, size_t ws_size,
                              hipStream_t stream) {
    const float* pred    = (const float*)d_in[0];   // [C, H, W]
    const float* gt      = (const float*)d_in[1];   // [B, C]
    const float* heatmap = (const float*)d_in[2];   // [B, H, W]
    float* out = (float*)d_out;
    unsigned long long* part = (unsigned long long*)d_ws;        // 16 KB
    unsigned int* counter = (unsigned int*)((char*)d_ws + NBLK * sizeof(unsigned long long));

    fused_kernel<<<NBLK, TPB, 0, stream>>>(heatmap, pred, gt, part, counter, out);
}

// Round 4
// 204.177 us; speedup vs baseline: 1.8052x; 1.8052x over previous
//
#include <hip/hip_runtime.h>
#include <math.h>

#define C_DIM 16
#define B_DIM 128
#define H_DIM 512
#define W_DIM 512
#define HW (H_DIM * W_DIM)      // 262144
#define BPS 16                  // blocks per sample
#define TPB 256
#define VEC_PER_CHUNK (HW / 4 / BPS)   // 4096 float4 per block

__device__ __forceinline__ unsigned int mono_bits(float x) {
    unsigned int u = __float_as_uint(x);
    // monotone map: orders all floats (incl. negatives) as unsigned
    return (u & 0x80000000u) ? ~u : (u | 0x80000000u);
}

__device__ __forceinline__ unsigned long long pack_key(float v, unsigned int idx) {
    // high word: monotone value bits; low word: ~idx so LOWER index wins ties
    return ((unsigned long long)mono_bits(v) << 32) | (unsigned long long)(~idx);
}

// Stage 1: per-(sample,chunk) partial argmax.
// Inner loop is v_max3-based (~2.5 VALU ops/elem): track the running max value
// plus the float4 + base index where it was found; strictly-greater update
// preserves first-occurrence semantics (thread-local indices are monotone).
// Key packing happens once per thread, after the loop.
__global__ __launch_bounds__(TPB) void argmax_partial_kernel(
        const float* __restrict__ heatmap,
        unsigned long long* __restrict__ part /* [B*BPS], fully overwritten */) {
    const int b     = blockIdx.x / BPS;
    const int chunk = blockIdx.x % BPS;
    const float4* hp = (const float4*)(heatmap + (size_t)b * HW);
    const int vbase = chunk * VEC_PER_CHUNK;

    float  m  = -INFINITY;
    float4 sv = make_float4(-INFINITY, -INFINITY, -INFINITY, -INFINITY);
    int    si = vbase * 4;      // element base index of sv

    #pragma unroll 4
    for (int i = threadIdx.x; i < VEC_PER_CHUNK; i += TPB) {
        float4 v = hp[vbase + i];
        float m4 = fmaxf(fmaxf(fmaxf(v.x, v.y), v.z), v.w);   // v_max3 + v_max
        if (m4 > m) {           // strict > keeps earliest occurrence
            m  = m4;
            sv = v;
            si = (vbase + i) * 4;
        }
    }

    // which element of the saved vector hit the max (first match = lowest idx)
    unsigned int j = (sv.x == m) ? 0u : (sv.y == m) ? 1u : (sv.z == m) ? 2u : 3u;
    unsigned long long k = pack_key(m, (unsigned int)si + j);

    // wave(64) shuffle reduce
    #pragma unroll
    for (int off = 32; off > 0; off >>= 1) {
        unsigned long long o = __shfl_down(k, off, 64);
        if (o > k) k = o;
    }
    __shared__ unsigned long long smax[TPB / 64];
    const int lane = threadIdx.x & 63;
    const int wid  = threadIdx.x >> 6;
    if (lane == 0) smax[wid] = k;
    __syncthreads();
    if (threadIdx.x == 0) {
        k = smax[0];
        #pragma unroll
        for (int w = 1; w < TPB / 64; ++w)
            if (smax[w] > k) k = smax[w];
        part[blockIdx.x] = k;   // plain store — no memset, no atomics
    }
}

// Stage 2: final 16-way key reduce per sample + gather + squared-error sum.
__global__ __launch_bounds__(B_DIM) void loss_kernel(
        const float* __restrict__ pred,
        const float* __restrict__ gt,
        const unsigned long long* __restrict__ part,
        float* __restrict__ out) {
    const int b = threadIdx.x;           // one thread per sample, 2 waves
    unsigned long long k = 0ull;
    #pragma unroll
    for (int j = 0; j < BPS; ++j) {
        unsigned long long o = part[b * BPS + j];
        if (o > k) k = o;
    }
    unsigned int idx = ~(unsigned int)(k & 0xFFFFFFFFull);   // flat H*W index

    float acc = 0.f;
    #pragma unroll
    for (int c = 0; c < C_DIM; ++c) {
        float d = pred[(size_t)c * HW + idx] - gt[b * C_DIM + c];
        acc += d * d;
    }
    // reduce across 128 threads: wave shuffle then LDS
    #pragma unroll
    for (int off = 32; off > 0; off >>= 1)
        acc += __shfl_down(acc, off, 64);
    __shared__ float spart[B_DIM / 64];
    if ((threadIdx.x & 63) == 0) spart[threadIdx.x >> 6] = acc;
    __syncthreads();
    if (threadIdx.x == 0) out[0] = spart[0] + spart[1];
}

extern "C" void kernel_launch(void* const* d_in, const int* in_sizes, int n_in,
                              void* d_out, int out_size, void* d_ws, size_t ws_size,
                              hipStream_t stream) {
    const float* pred    = (const float*)d_in[0];   // [C, H, W]
    const float* gt      = (const float*)d_in[1];   // [B, C]
    const float* heatmap = (const float*)d_in[2];   // [B, H, W]
    float* out = (float*)d_out;
    unsigned long long* part = (unsigned long long*)d_ws;   // [B*BPS] = 16 KB

    argmax_partial_kernel<<<B_DIM * BPS, TPB, 0, stream>>>(heatmap, part);
    loss_kernel<<<1, B_DIM, 0, stream>>>(pred, gt, part, out);
}